// Round 10
// baseline (1054.030 us; speedup 1.0000x reference)
//
#include <hip/hip_runtime.h>
#include <hip/hip_bf16.h>

// Problem constants
#define IN_DIM 64
#define H_DIM 128
#define L_LAYERS 3
#define G_GRAPHS 256
#define C_CLASSES 10
#define BN_BLOCKS 512

typedef short bf16x8 __attribute__((ext_vector_type(8)));
typedef float f32x4 __attribute__((ext_vector_type(4)));

__device__ inline unsigned short bf16rne(float x) {
    unsigned v = __float_as_uint(x);
    v += 0x7FFFu + ((v >> 16) & 1u);
    return (unsigned short)(v >> 16);
}

// RNE split: x = hi + lo + eps, |eps| <~ 2^-17 |x|.
__device__ inline void bsplit(float x, unsigned short& h, unsigned short& l) {
    h = bf16rne(x);
    float hf = __uint_as_float((unsigned)h << 16);
    l = bf16rne(x - hf);
}

// ---------------------------------------------------------------------------
// CSR build (atomic-free scatter: count pass records per-edge rank)
// ---------------------------------------------------------------------------
__global__ void count_deg(const int* __restrict__ dst, int* __restrict__ deg,
                          int* __restrict__ erank, int e) {
    int i = blockIdx.x * blockDim.x + threadIdx.x;
    if (i < e) erank[i] = atomicAdd(&deg[dst[i]], 1);
}

__global__ __launch_bounds__(256) void scan1(const int* __restrict__ deg,
                                             int* __restrict__ rowptr,
                                             int* __restrict__ bsum, int n) {
    int i = blockIdx.x * 256 + threadIdx.x;
    int v = (i < n) ? deg[i] : 0;
    __shared__ int sm[256];
    sm[threadIdx.x] = v;
    __syncthreads();
    for (int off = 1; off < 256; off <<= 1) {
        int x = (threadIdx.x >= off) ? sm[threadIdx.x - off] : 0;
        __syncthreads();
        sm[threadIdx.x] += x;
        __syncthreads();
    }
    if (i < n) rowptr[i + 1] = sm[threadIdx.x];
    if (threadIdx.x == 255) bsum[blockIdx.x] = sm[255];
}

__global__ __launch_bounds__(512) void scan2(int* __restrict__ bsum, int nblk) {
    __shared__ int sm[512];
    int t = threadIdx.x;
    int v = (t < nblk) ? bsum[t] : 0;
    sm[t] = v;
    __syncthreads();
    for (int off = 1; off < 512; off <<= 1) {
        int x = (t >= off) ? sm[t - off] : 0;
        __syncthreads();
        sm[t] += x;
        __syncthreads();
    }
    if (t < nblk) bsum[t] = sm[t] - v;  // exclusive
}

__global__ void scan3(int* __restrict__ rowptr, const int* __restrict__ bsum, int n) {
    int i = blockIdx.x * 256 + threadIdx.x;
    if (i < n) rowptr[i + 1] += bsum[i >> 8];
    if (i == 0) rowptr[0] = 0;
}

__global__ void scatter_edges(const int* __restrict__ src, const int* __restrict__ dst,
                              const int* __restrict__ rowptr, const int* __restrict__ erank,
                              int* __restrict__ esrc, int e) {
    int i = blockIdx.x * blockDim.x + threadIdx.x;
    if (i < e) esrc[rowptr[dst[i]] + erank[i]] = src[i];
}

// ---------------------------------------------------------------------------
// prep_w: fp32 weights [K][128] -> fragment-major hi/lo bf16 (B-operand).
// frag f = (col>>4)*(K>>5) + (k>>5); lane = ((k>>3)&3)*16 + (col&15); j = k&7.
// ---------------------------------------------------------------------------
template <int K>
__device__ inline void prep_w_one(const float* __restrict__ W,
                                  unsigned short* __restrict__ WFm, int e8) {
    const int GPC = K / 8;
    if (e8 >= K * 16) return;
    int col = e8 / GPC;
    int k0 = (e8 - col * GPC) * 8;
    float v[8];
#pragma unroll
    for (int j = 0; j < 8; ++j) v[j] = W[(size_t)(k0 + j) * 128 + col];
    unsigned short h[8], l[8];
#pragma unroll
    for (int j = 0; j < 8; ++j) bsplit(v[j], h[j], l[j]);
    size_t f = (size_t)(col >> 4) * (K >> 5) + (k0 >> 5);
    int lane = ((k0 >> 3) & 3) * 16 + (col & 15);
    unsigned short* p = WFm + f * 1024 + lane * 8;
    uint4 hv, lv;
    hv.x = h[0] | (h[1] << 16); hv.y = h[2] | (h[3] << 16);
    hv.z = h[4] | (h[5] << 16); hv.w = h[6] | (h[7] << 16);
    lv.x = l[0] | (l[1] << 16); lv.y = l[2] | (l[3] << 16);
    lv.z = l[4] | (l[5] << 16); lv.w = l[6] | (l[7] << 16);
    *(uint4*)p = hv;
    *(uint4*)(p + 512) = lv;
}

__global__ __launch_bounds__(256) void prep_w64(const float* __restrict__ W0,
                                                const float* __restrict__ W1,
                                                const float* __restrict__ W2,
                                                const float* __restrict__ W3,
                                                unsigned short* __restrict__ WF) {
    const float* W = (blockIdx.y == 0) ? W0 : (blockIdx.y == 1) ? W1
                   : (blockIdx.y == 2) ? W2 : W3;
    prep_w_one<IN_DIM>(W, WF + (size_t)blockIdx.y * 16384,
                       blockIdx.x * 256 + threadIdx.x);
}

__global__ __launch_bounds__(256) void prep_w128(const float* __restrict__ Wq,
                                                 const float* __restrict__ Wk,
                                                 const float* __restrict__ Wv,
                                                 const float* __restrict__ Ws,
                                                 unsigned short* __restrict__ WF) {
    int layer = blockIdx.y >> 2, mat = blockIdx.y & 3;
    const float* base = (mat == 0) ? Wq : (mat == 1) ? Wk : (mat == 2) ? Wv : Ws;
    const float* W = base + (size_t)layer * H_DIM * H_DIM;
    unsigned short* o = WF + 65536 + (size_t)blockIdx.y * 32768;
    prep_w_one<H_DIM>(W, o, blockIdx.x * 256 + threadIdx.x);
}

// ---------------------------------------------------------------------------
// Fused GEMM, y-pair grid split: blockIdx.y=0 computes {q,k}, =1 computes
// {v,skip}. 2x waves vs round-7 (12->24 waves/CU) to fix the grid-capped
// occupancy (31%, both pipes 18% busy). Same per-output FP order.
// A-fragments built in-reg from fp32 X (+BN+ReLU), 3-term split (hh+hl+lh).
// ---------------------------------------------------------------------------
template <int K, bool BN>
__global__ __launch_bounds__(256) void gemm_fused(
    const float* __restrict__ X, const unsigned short* __restrict__ WF,
    int n, int strips,
    const float* __restrict__ bnsc, const float* __restrict__ bnsh,
    const float* __restrict__ b0, const float* __restrict__ b1,
    const float* __restrict__ b2, const float* __restrict__ b3,
    float* __restrict__ oq, unsigned short* __restrict__ okv,
    float* __restrict__ oskip) {
    constexpr int KB = K >> 5;
    int wid = (blockIdx.x * 256 + threadIdx.x) >> 6;
    int l = threadIdx.x & 63;
    if (wid >= strips) return;
    const int r16 = l & 15;
    const int ko8 = (l >> 4) * 8;
    const int ybase = blockIdx.y * 2;   // 0 -> {q,k}, 2 -> {v,skip}

    // A fragments: load fp32 rows in fragment order, BN+ReLU, split hi/lo.
    bf16x8 A[2][KB][2];
#pragma unroll
    for (int kb = 0; kb < KB; ++kb) {
        float sc[8], sh[8];
        if (BN) {
            *(float4*)sc       = *(const float4*)(bnsc + kb * 32 + ko8);
            *(float4*)(sc + 4) = *(const float4*)(bnsc + kb * 32 + ko8 + 4);
            *(float4*)sh       = *(const float4*)(bnsh + kb * 32 + ko8);
            *(float4*)(sh + 4) = *(const float4*)(bnsh + kb * 32 + ko8 + 4);
        }
#pragma unroll
        for (int mf = 0; mf < 2; ++mf) {
            int row = wid * 32 + mf * 16 + r16;
            int rowc = row < n ? row : n - 1;
            const float* px = X + (size_t)rowc * K + kb * 32 + ko8;
            float v[8];
            *(float4*)v       = *(const float4*)px;
            *(float4*)(v + 4) = *(const float4*)(px + 4);
            if (BN) {
#pragma unroll
                for (int j = 0; j < 8; ++j) v[j] = fmaxf(0.f, fmaf(v[j], sc[j], sh[j]));
            }
            bf16x8 hi, lo;
#pragma unroll
            for (int j = 0; j < 8; ++j) {
                unsigned short h, l2;
                bsplit(v[j], h, l2);
                hi[j] = (short)h; lo[j] = (short)l2;
            }
            A[mf][kb][0] = hi;
            A[mf][kb][1] = lo;
        }
    }

    const int rbase = wid * 32 + ((l >> 4) << 2);
#pragma unroll
    for (int nf = 0; nf < 8; ++nf) {
        const int col = nf * 16 + (l & 15);
#pragma unroll
        for (int yy = 0; yy < 2; ++yy) {
            const int y = ybase + yy;
            const float* bias = (y == 0) ? b0 : (y == 1) ? b1 : (y == 2) ? b2 : b3;
            const unsigned short* WFy = WF + (size_t)y * (8 * KB * 1024);
            bf16x8 B[KB][2];
#pragma unroll
            for (int kb = 0; kb < KB; ++kb) {
                const unsigned short* p = WFy + ((size_t)(nf * KB + kb)) * 1024 + l * 8;
                B[kb][0] = *(const bf16x8*)p;
                B[kb][1] = *(const bf16x8*)(p + 512);
            }
            f32x4 acc[2];
            acc[0] = (f32x4){0.f, 0.f, 0.f, 0.f};
            acc[1] = (f32x4){0.f, 0.f, 0.f, 0.f};
#pragma unroll
            for (int kb = 0; kb < KB; ++kb) {
#pragma unroll
                for (int mf = 0; mf < 2; ++mf) {
                    acc[mf] = __builtin_amdgcn_mfma_f32_16x16x32_bf16(
                        A[mf][kb][0], B[kb][0], acc[mf], 0, 0, 0);
                    acc[mf] = __builtin_amdgcn_mfma_f32_16x16x32_bf16(
                        A[mf][kb][0], B[kb][1], acc[mf], 0, 0, 0);
                    acc[mf] = __builtin_amdgcn_mfma_f32_16x16x32_bf16(
                        A[mf][kb][1], B[kb][0], acc[mf], 0, 0, 0);
                }
            }
            float bb = bias[col];
            if (y == 0 || y == 3) {
                float* outp = (y == 0) ? oq : oskip;
#pragma unroll
                for (int mf = 0; mf < 2; ++mf)
#pragma unroll
                    for (int r = 0; r < 4; ++r) {
                        int row = rbase + mf * 16 + r;
                        if (row < n) outp[(size_t)row * 128 + col] = acc[mf][r] + bb;
                    }
            } else {
                const int voff = (y == 2) ? 128 : 0;
#pragma unroll
                for (int mf = 0; mf < 2; ++mf)
#pragma unroll
                    for (int r = 0; r < 4; ++r) {
                        int row = rbase + mf * 16 + r;
                        if (row < n)
                            okv[(size_t)row * 256 + voff + col] = bf16rne(acc[mf][r] + bb);
                    }
            }
        }
    }
}

// ---------------------------------------------------------------------------
// Per-target edge attention, online softmax. Two 32-lane halves per wave, each
// owning one edge (4 feats/lane); states merged via shfl_xor(32). Guarded
// prefetch, 2-chunk pipeline.
// ---------------------------------------------------------------------------
__global__ __launch_bounds__(256) void attn_kernel(
    const float* __restrict__ q, const unsigned short* __restrict__ kv,
    const int* __restrict__ rowptr, const int* __restrict__ esrc,
    float* __restrict__ h2, int n) {
    int wid = (blockIdx.x * blockDim.x + threadIdx.x) >> 6;
    int lane = threadIdx.x & 63;
    if (wid >= n) return;
    const int g = lane >> 5;       // half id: edge j+g
    const int f0 = (lane & 31) * 4;
    float4 qv = *(const float4*)(q + (size_t)wid * 128 + f0);
    const float scale = 0.08838834764831845f;  // 1/sqrt(128)
    int beg = rowptr[wid], end = rowptr[wid + 1];
    if (beg == end) return;  // no in-edges: h2 stays = skip term (matches ref)
    float m = -3.402823466e38f, ssum = 0.f;
    float a0 = 0.f, a1 = 0.f, a2 = 0.f, a3 = 0.f;

#define FETCH(J, KU, VU) {                                                   \
        int jj = (J) + g;                                                    \
        if (jj < end) {                                                      \
            int s = esrc[jj];                                                \
            const unsigned short* p = kv + (size_t)s * 256 + f0;             \
            KU = *(const uint2*)p;                                           \
            VU = *(const uint2*)(p + 128);                                   \
        } else { KU.x = 0u; KU.y = 0u; VU.x = 0u; VU.y = 0u; } }

#define PROC(J, KU, VU) {                                                    \
        float kx0 = __uint_as_float(KU.x << 16);                             \
        float kx1 = __uint_as_float(KU.x & 0xFFFF0000u);                     \
        float kx2 = __uint_as_float(KU.y << 16);                             \
        float kx3 = __uint_as_float(KU.y & 0xFFFF0000u);                     \
        float d = qv.x * kx0 + qv.y * kx1 + qv.z * kx2 + qv.w * kx3;         \
        d += __shfl_xor(d, 1);  d += __shfl_xor(d, 2);  d += __shfl_xor(d, 4); \
        d += __shfl_xor(d, 8);  d += __shfl_xor(d, 16);                      \
        d *= scale;                                                          \
        if ((J) + g < end) {                                                 \
            if (d > m) {                                                     \
                float r = __expf(m - d);                                     \
                ssum *= r; a0 *= r; a1 *= r; a2 *= r; a3 *= r; m = d;        \
            }                                                                \
            float w = __expf(d - m);                                         \
            ssum += w;                                                       \
            a0 += w * __uint_as_float(VU.x << 16);                           \
            a1 += w * __uint_as_float(VU.x & 0xFFFF0000u);                   \
            a2 += w * __uint_as_float(VU.y << 16);                           \
            a3 += w * __uint_as_float(VU.y & 0xFFFF0000u);                   \
        } }

    uint2 kA, vA, kB, vB;
    FETCH(beg, kA, vA);
    FETCH(beg + 2, kB, vB);
    int j = beg;
    for (;;) {
        {
            uint2 kN, vN;
            FETCH(j + 4, kN, vN);
            PROC(j, kA, vA);
            kA = kN; vA = vN;
        }
        j += 2; if (j >= end) break;
        {
            uint2 kN, vN;
            FETCH(j + 4, kN, vN);
            PROC(j, kB, vB);
            kB = kN; vB = vN;
        }
        j += 2; if (j >= end) break;
    }
#undef FETCH
#undef PROC

    // merge the two halves' online-softmax states (butterfly, both get result)
    float mo = __shfl_xor(m, 32);
    float m2 = fmaxf(m, mo);
    float fac = __expf(m - m2);      // 0 if this half processed no edges
    ssum *= fac; a0 *= fac; a1 *= fac; a2 *= fac; a3 *= fac;
    ssum += __shfl_xor(ssum, 32);
    a0 += __shfl_xor(a0, 32);
    a1 += __shfl_xor(a1, 32);
    a2 += __shfl_xor(a2, 32);
    a3 += __shfl_xor(a3, 32);
    if (lane < 32) {
        float inv = 1.f / ssum;
        float4* o = (float4*)(h2 + (size_t)wid * 128 + f0);
        float4 cur = *o;
        cur.x += a0 * inv;
        cur.y += a1 * inv;
        cur.z += a2 * inv;
        cur.w += a3 * inv;
        *o = cur;
    }
}

// ---------------------------------------------------------------------------
// BatchNorm stats: vectorized float4 loads, BN_BLOCKS blocks (was scalar/256).
// ---------------------------------------------------------------------------
__global__ __launch_bounds__(256) void bn_stats(const float* __restrict__ h2,
                                                float* __restrict__ psum,
                                                float* __restrict__ psq, int n) {
    int q4 = (threadIdx.x & 31) * 4;
    int rp = threadIdx.x >> 5;  // 0..7
    float4 s = make_float4(0.f, 0.f, 0.f, 0.f);
    float4 s2 = make_float4(0.f, 0.f, 0.f, 0.f);
    for (int r = blockIdx.x * 8 + rp; r < n; r += gridDim.x * 8) {
        float4 x = *(const float4*)(h2 + (size_t)r * 128 + q4);
        s.x += x.x; s.y += x.y; s.z += x.z; s.w += x.w;
        s2.x += x.x * x.x; s2.y += x.y * x.y; s2.z += x.z * x.z; s2.w += x.w * x.w;
    }
    __shared__ float4 smS[256], smQ[256];
    smS[threadIdx.x] = s;
    smQ[threadIdx.x] = s2;
    __syncthreads();
    if (rp == 0) {
        int t = threadIdx.x;  // 0..31
#pragma unroll
        for (int i = 1; i < 8; ++i) {
            float4 a = smS[t + 32 * i], b = smQ[t + 32 * i];
            s.x += a.x; s.y += a.y; s.z += a.z; s.w += a.w;
            s2.x += b.x; s2.y += b.y; s2.z += b.z; s2.w += b.w;
        }
        *(float4*)(psum + (size_t)blockIdx.x * 128 + q4) = s;
        *(float4*)(psq + (size_t)blockIdx.x * 128 + q4) = s2;
    }
}

__global__ __launch_bounds__(512) void bn_finalize(const float* __restrict__ psum,
                                                   const float* __restrict__ psq,
                                                   const float* __restrict__ g,
                                                   const float* __restrict__ b,
                                                   float* __restrict__ scale,
                                                   float* __restrict__ shift,
                                                   int n, int nblk) {
    int f = threadIdx.x & 127, part = threadIdx.x >> 7;
    float s = 0.f, s2 = 0.f;
    for (int i = part; i < nblk; i += 4) {
        s += psum[i * 128 + f];
        s2 += psq[i * 128 + f];
    }
    __shared__ float sa[512], sb[512];
    sa[threadIdx.x] = s;
    sb[threadIdx.x] = s2;
    __syncthreads();
    if (part == 0) {
        s = sa[f] + sa[128 + f] + sa[256 + f] + sa[384 + f];
        s2 = sb[f] + sb[128 + f] + sb[256 + f] + sb[384 + f];
        float inv_n = 1.f / (float)n;
        float mu = s * inv_n;
        float var = s2 * inv_n - mu * mu;
        float sc = g[f] * rsqrtf(var + 1e-5f);
        scale[f] = sc;
        shift[f] = b[f] - mu * sc;
    }
}

// ---------------------------------------------------------------------------
// Pool (fused last BN+ReLU) + head
// ---------------------------------------------------------------------------
__global__ __launch_bounds__(256) void pool_kernel(const float* __restrict__ h,
                                                   const float* __restrict__ bnsc,
                                                   const float* __restrict__ bnsh,
                                                   const int* __restrict__ batch,
                                                   float* __restrict__ pooled, int n) {
    int g = blockIdx.x;
    int lo = 0, hi = n;
    while (lo < hi) { int mid = (lo + hi) >> 1; if (batch[mid] < g) lo = mid + 1; else hi = mid; }
    int start = lo;
    lo = start; hi = n;
    while (lo < hi) { int mid = (lo + hi) >> 1; if (batch[mid] < g + 1) lo = mid + 1; else hi = mid; }
    int end = lo;
    int f = threadIdx.x & 127, rp = threadIdx.x >> 7;
    float sc = bnsc[f], sh = bnsh[f];
    float s = 0.f;
    for (int r = start + rp; r < end; r += 2)
        s += fmaxf(0.f, fmaf(h[(size_t)r * 128 + f], sc, sh));
    __shared__ float sm[256];
    sm[threadIdx.x] = s;
    __syncthreads();
    if (rp == 0) {
        float tot = sm[f] + sm[128 + f];
        float cnt = (float)(end - start);
        pooled[g * 128 + f] = tot / fmaxf(cnt, 1.f);
    }
}

__global__ void head_kernel(const float* __restrict__ pooled, const float* __restrict__ W,
                            const float* __restrict__ bias, float* __restrict__ out) {
    int g = blockIdx.x;
    int lane = threadIdx.x;  // 64
    float p0 = pooled[g * 128 + lane];
    float p1 = pooled[g * 128 + 64 + lane];
#pragma unroll
    for (int c = 0; c < C_CLASSES; ++c) {
        float d = p0 * W[lane * C_CLASSES + c] + p1 * W[(64 + lane) * C_CLASSES + c];
#pragma unroll
        for (int off = 32; off; off >>= 1) d += __shfl_xor(d, off);
        if (lane == 0) out[g * C_CLASSES + c] = d + bias[c];
    }
}

// ---------------------------------------------------------------------------
extern "C" void kernel_launch(void* const* d_in, const int* in_sizes, int n_in,
                              void* d_out, int out_size, void* d_ws, size_t ws_size,
                              hipStream_t stream) {
    const int N = in_sizes[0] / IN_DIM;       // 100000
    const int E = in_sizes[1] / 2;            // 600000

    const float* x     = (const float*)d_in[0];
    const int* ei      = (const int*)d_in[1];
    const int* src     = ei;
    const int* dst     = ei + E;
    const int* batch   = (const int*)d_in[2];
    const float* Wq1 = (const float*)d_in[3],  *bq1 = (const float*)d_in[4];
    const float* Wk1 = (const float*)d_in[5],  *bk1 = (const float*)d_in[6];
    const float* Wv1 = (const float*)d_in[7],  *bv1 = (const float*)d_in[8];
    const float* Ws1 = (const float*)d_in[9],  *bs1 = (const float*)d_in[10];
    const float* bn1g = (const float*)d_in[11], *bn1b = (const float*)d_in[12];
    const float* Wq = (const float*)d_in[13], *bq = (const float*)d_in[14];
    const float* Wk = (const float*)d_in[15], *bk = (const float*)d_in[16];
    const float* Wv = (const float*)d_in[17], *bv = (const float*)d_in[18];
    const float* Ws = (const float*)d_in[19], *bs = (const float*)d_in[20];
    const float* bng = (const float*)d_in[21], *bnb = (const float*)d_in[22];
    const float* linW = (const float*)d_in[23], *linb = (const float*)d_in[24];
    float* out = (float*)d_out;

    const int strips = (N + 31) / 32;         // 3125 (N % 32 == 0)

    // workspace layout
    char* w = (char*)d_ws;
    auto alloc = [&](size_t bytes) -> char* {
        char* p = w;
        w += (bytes + 255) & ~(size_t)255;
        return p;
    };
    const size_t NH = (size_t)N * H_DIM;
    float* q     = (float*)alloc(NH * 4);
    float* convA = (float*)alloc(NH * 4);
    float* convB = (float*)alloc(NH * 4);
    unsigned short* kv16 = (unsigned short*)alloc((size_t)N * 256 * 2);
    unsigned short* WF   = (unsigned short*)alloc((size_t)(65536 + 12 * 32768) * 2);
    float* psum = (float*)alloc((size_t)BN_BLOCKS * 128 * 4);
    float* psq  = (float*)alloc((size_t)BN_BLOCKS * 128 * 4);
    float* bnsc = (float*)alloc(128 * 4);
    float* bnsh = (float*)alloc(128 * 4);
    float* pooled = (float*)alloc(G_GRAPHS * H_DIM * 4);
    int* deg    = (int*)alloc((size_t)N * 4);
    int* rowptr = (int*)alloc((size_t)(N + 1) * 4);
    int* erank  = (int*)alloc((size_t)E * 4);
    int* esrc   = (int*)alloc((size_t)E * 4);
    int* bsum   = (int*)alloc(((size_t)(N + 255) / 256) * 4);

    const int nblk = (N + 255) / 256;
    const int egrid = (E + 255) / 256;

    // ---- CSR build + all weight prep (independent, up-front)
    hipMemsetAsync(deg, 0, (size_t)N * 4, stream);
    count_deg<<<egrid, 256, 0, stream>>>(dst, deg, erank, E);
    prep_w64<<<dim3(4, 4), 256, 0, stream>>>(Wq1, Wk1, Wv1, Ws1, WF);
    prep_w128<<<dim3(8, 12), 256, 0, stream>>>(Wq, Wk, Wv, Ws, WF);
    scan1<<<nblk, 256, 0, stream>>>(deg, rowptr, bsum, N);
    scan2<<<1, 512, 0, stream>>>(bsum, nblk);
    scan3<<<nblk, 256, 0, stream>>>(rowptr, bsum, N);
    scatter_edges<<<egrid, 256, 0, stream>>>(src, dst, rowptr, erank, esrc, E);

    const int attn_blocks = (N + 3) / 4;
    const int gemm_blocks = (strips + 3) / 4;

    // ---- layer 1 (K=64, raw input, no BN)
    gemm_fused<IN_DIM, false><<<dim3(gemm_blocks, 2), 256, 0, stream>>>(
        x, WF, N, strips, nullptr, nullptr, bq1, bk1, bv1, bs1, q, kv16, convA);
    attn_kernel<<<attn_blocks, 256, 0, stream>>>(q, kv16, rowptr, esrc, convA, N);
    bn_stats<<<BN_BLOCKS, 256, 0, stream>>>(convA, psum, psq, N);
    bn_finalize<<<1, 512, 0, stream>>>(psum, psq, bn1g, bn1b, bnsc, bnsh, N, BN_BLOCKS);

    // ---- layers 2..4 (K=128, prev BN+ReLU fused into gemm A-load)
    float* cur = convA;
    float* nxt = convB;
    for (int i = 0; i < L_LAYERS; ++i) {
        const size_t bo = (size_t)i * H_DIM;
        const unsigned short* WFl = WF + 65536 + (size_t)i * 4 * 32768;
        gemm_fused<H_DIM, true><<<dim3(gemm_blocks, 2), 256, 0, stream>>>(
            cur, WFl, N, strips, bnsc, bnsh, bq + bo, bk + bo, bv + bo, bs + bo,
            q, kv16, nxt);
        attn_kernel<<<attn_blocks, 256, 0, stream>>>(q, kv16, rowptr, esrc, nxt, N);
        bn_stats<<<BN_BLOCKS, 256, 0, stream>>>(nxt, psum, psq, N);
        bn_finalize<<<1, 512, 0, stream>>>(psum, psq, bng + bo, bnb + bo, bnsc, bnsh, N, BN_BLOCKS);
        float* t = cur; cur = nxt; nxt = t;
    }

    // ---- pool (fused last BN+ReLU) + head
    pool_kernel<<<G_GRAPHS, 256, 0, stream>>>(cur, bnsc, bnsh, batch, pooled, N);
    head_kernel<<<G_GRAPHS, 64, 0, stream>>>(pooled, linW, linb, out);
}

// Round 11
// 970.337 us; speedup vs baseline: 1.0863x; 1.0863x over previous
//
#include <hip/hip_runtime.h>
#include <hip/hip_bf16.h>

// Problem constants
#define IN_DIM 64
#define H_DIM 128
#define L_LAYERS 3
#define G_GRAPHS 256
#define C_CLASSES 10
#define BN_BLOCKS 512

typedef short bf16x8 __attribute__((ext_vector_type(8)));
typedef float f32x4 __attribute__((ext_vector_type(4)));

__device__ inline unsigned short bf16rne(float x) {
    unsigned v = __float_as_uint(x);
    v += 0x7FFFu + ((v >> 16) & 1u);
    return (unsigned short)(v >> 16);
}

// RNE split: x = hi + lo + eps, |eps| <~ 2^-17 |x|.
__device__ inline void bsplit(float x, unsigned short& h, unsigned short& l) {
    h = bf16rne(x);
    float hf = __uint_as_float((unsigned)h << 16);
    l = bf16rne(x - hf);
}

// ---------------------------------------------------------------------------
// CSR build (atomic-free scatter: count pass records per-edge rank)
// ---------------------------------------------------------------------------
__global__ void count_deg(const int* __restrict__ dst, int* __restrict__ deg,
                          int* __restrict__ erank, int e) {
    int i = blockIdx.x * blockDim.x + threadIdx.x;
    if (i < e) erank[i] = atomicAdd(&deg[dst[i]], 1);
}

__global__ __launch_bounds__(256) void scan1(const int* __restrict__ deg,
                                             int* __restrict__ rowptr,
                                             int* __restrict__ bsum, int n) {
    int i = blockIdx.x * 256 + threadIdx.x;
    int v = (i < n) ? deg[i] : 0;
    __shared__ int sm[256];
    sm[threadIdx.x] = v;
    __syncthreads();
    for (int off = 1; off < 256; off <<= 1) {
        int x = (threadIdx.x >= off) ? sm[threadIdx.x - off] : 0;
        __syncthreads();
        sm[threadIdx.x] += x;
        __syncthreads();
    }
    if (i < n) rowptr[i + 1] = sm[threadIdx.x];
    if (threadIdx.x == 255) bsum[blockIdx.x] = sm[255];
}

__global__ __launch_bounds__(512) void scan2(int* __restrict__ bsum, int nblk) {
    __shared__ int sm[512];
    int t = threadIdx.x;
    int v = (t < nblk) ? bsum[t] : 0;
    sm[t] = v;
    __syncthreads();
    for (int off = 1; off < 512; off <<= 1) {
        int x = (t >= off) ? sm[t - off] : 0;
        __syncthreads();
        sm[t] += x;
        __syncthreads();
    }
    if (t < nblk) bsum[t] = sm[t] - v;  // exclusive
}

__global__ void scan3(int* __restrict__ rowptr, const int* __restrict__ bsum, int n) {
    int i = blockIdx.x * 256 + threadIdx.x;
    if (i < n) rowptr[i + 1] += bsum[i >> 8];
    if (i == 0) rowptr[0] = 0;
}

__global__ void scatter_edges(const int* __restrict__ src, const int* __restrict__ dst,
                              const int* __restrict__ rowptr, const int* __restrict__ erank,
                              int* __restrict__ esrc, int e) {
    int i = blockIdx.x * blockDim.x + threadIdx.x;
    if (i < e) esrc[rowptr[dst[i]] + erank[i]] = src[i];
}

// ---------------------------------------------------------------------------
// prep_w: fp32 weights [K][128] -> fragment-major hi/lo bf16 (B-operand).
// frag f = (col>>4)*(K>>5) + (k>>5); lane = ((k>>3)&3)*16 + (col&15); j = k&7.
// ---------------------------------------------------------------------------
template <int K>
__device__ inline void prep_w_one(const float* __restrict__ W,
                                  unsigned short* __restrict__ WFm, int e8) {
    const int GPC = K / 8;
    if (e8 >= K * 16) return;
    int col = e8 / GPC;
    int k0 = (e8 - col * GPC) * 8;
    float v[8];
#pragma unroll
    for (int j = 0; j < 8; ++j) v[j] = W[(size_t)(k0 + j) * 128 + col];
    unsigned short h[8], l[8];
#pragma unroll
    for (int j = 0; j < 8; ++j) bsplit(v[j], h[j], l[j]);
    size_t f = (size_t)(col >> 4) * (K >> 5) + (k0 >> 5);
    int lane = ((k0 >> 3) & 3) * 16 + (col & 15);
    unsigned short* p = WFm + f * 1024 + lane * 8;
    uint4 hv, lv;
    hv.x = h[0] | (h[1] << 16); hv.y = h[2] | (h[3] << 16);
    hv.z = h[4] | (h[5] << 16); hv.w = h[6] | (h[7] << 16);
    lv.x = l[0] | (l[1] << 16); lv.y = l[2] | (l[3] << 16);
    lv.z = l[4] | (l[5] << 16); lv.w = l[6] | (l[7] << 16);
    *(uint4*)p = hv;
    *(uint4*)(p + 512) = lv;
}

__global__ __launch_bounds__(256) void prep_w64(const float* __restrict__ W0,
                                                const float* __restrict__ W1,
                                                const float* __restrict__ W2,
                                                const float* __restrict__ W3,
                                                unsigned short* __restrict__ WF) {
    const float* W = (blockIdx.y == 0) ? W0 : (blockIdx.y == 1) ? W1
                   : (blockIdx.y == 2) ? W2 : W3;
    prep_w_one<IN_DIM>(W, WF + (size_t)blockIdx.y * 16384,
                       blockIdx.x * 256 + threadIdx.x);
}

__global__ __launch_bounds__(256) void prep_w128(const float* __restrict__ Wq,
                                                 const float* __restrict__ Wk,
                                                 const float* __restrict__ Wv,
                                                 const float* __restrict__ Ws,
                                                 unsigned short* __restrict__ WF) {
    int layer = blockIdx.y >> 2, mat = blockIdx.y & 3;
    const float* base = (mat == 0) ? Wq : (mat == 1) ? Wk : (mat == 2) ? Wv : Ws;
    const float* W = base + (size_t)layer * H_DIM * H_DIM;
    unsigned short* o = WF + 65536 + (size_t)blockIdx.y * 32768;
    prep_w_one<H_DIM>(W, o, blockIdx.x * 256 + threadIdx.x);
}

// ---------------------------------------------------------------------------
// Fused GEMM (round-7 single-dispatch structure: one wave does all 4 outputs,
// A loaded once — minimal HBM traffic; the r10 y-split doubled FETCH and
// amplified kv partial-line writes, regressing). q now stored bf16 (only used
// in attn dot products; same error class as bf16 k). 3-term split (hh+hl+lh).
// ---------------------------------------------------------------------------
template <int K, bool BN>
__global__ __launch_bounds__(256) void gemm_fused(
    const float* __restrict__ X, const unsigned short* __restrict__ WF,
    int n, int strips,
    const float* __restrict__ bnsc, const float* __restrict__ bnsh,
    const float* __restrict__ b0, const float* __restrict__ b1,
    const float* __restrict__ b2, const float* __restrict__ b3,
    unsigned short* __restrict__ oq16, unsigned short* __restrict__ okv,
    float* __restrict__ oskip) {
    constexpr int KB = K >> 5;
    int wid = (blockIdx.x * 256 + threadIdx.x) >> 6;
    int l = threadIdx.x & 63;
    if (wid >= strips) return;
    const int r16 = l & 15;
    const int ko8 = (l >> 4) * 8;

    // A fragments: load fp32 rows in fragment order, BN+ReLU, split hi/lo.
    bf16x8 A[2][KB][2];
#pragma unroll
    for (int kb = 0; kb < KB; ++kb) {
        float sc[8], sh[8];
        if (BN) {
            *(float4*)sc       = *(const float4*)(bnsc + kb * 32 + ko8);
            *(float4*)(sc + 4) = *(const float4*)(bnsc + kb * 32 + ko8 + 4);
            *(float4*)sh       = *(const float4*)(bnsh + kb * 32 + ko8);
            *(float4*)(sh + 4) = *(const float4*)(bnsh + kb * 32 + ko8 + 4);
        }
#pragma unroll
        for (int mf = 0; mf < 2; ++mf) {
            int row = wid * 32 + mf * 16 + r16;
            int rowc = row < n ? row : n - 1;
            const float* px = X + (size_t)rowc * K + kb * 32 + ko8;
            float v[8];
            *(float4*)v       = *(const float4*)px;
            *(float4*)(v + 4) = *(const float4*)(px + 4);
            if (BN) {
#pragma unroll
                for (int j = 0; j < 8; ++j) v[j] = fmaxf(0.f, fmaf(v[j], sc[j], sh[j]));
            }
            bf16x8 hi, lo;
#pragma unroll
            for (int j = 0; j < 8; ++j) {
                unsigned short h, l2;
                bsplit(v[j], h, l2);
                hi[j] = (short)h; lo[j] = (short)l2;
            }
            A[mf][kb][0] = hi;
            A[mf][kb][1] = lo;
        }
    }

    const int rbase = wid * 32 + ((l >> 4) << 2);
#pragma unroll
    for (int nf = 0; nf < 8; ++nf) {
        const int col = nf * 16 + (l & 15);
#pragma unroll
        for (int y = 0; y < 4; ++y) {
            const float* bias = (y == 0) ? b0 : (y == 1) ? b1 : (y == 2) ? b2 : b3;
            const unsigned short* WFy = WF + (size_t)y * (8 * KB * 1024);
            bf16x8 B[KB][2];
#pragma unroll
            for (int kb = 0; kb < KB; ++kb) {
                const unsigned short* p = WFy + ((size_t)(nf * KB + kb)) * 1024 + l * 8;
                B[kb][0] = *(const bf16x8*)p;
                B[kb][1] = *(const bf16x8*)(p + 512);
            }
            f32x4 acc[2];
            acc[0] = (f32x4){0.f, 0.f, 0.f, 0.f};
            acc[1] = (f32x4){0.f, 0.f, 0.f, 0.f};
#pragma unroll
            for (int kb = 0; kb < KB; ++kb) {
#pragma unroll
                for (int mf = 0; mf < 2; ++mf) {
                    acc[mf] = __builtin_amdgcn_mfma_f32_16x16x32_bf16(
                        A[mf][kb][0], B[kb][0], acc[mf], 0, 0, 0);
                    acc[mf] = __builtin_amdgcn_mfma_f32_16x16x32_bf16(
                        A[mf][kb][0], B[kb][1], acc[mf], 0, 0, 0);
                    acc[mf] = __builtin_amdgcn_mfma_f32_16x16x32_bf16(
                        A[mf][kb][1], B[kb][0], acc[mf], 0, 0, 0);
                }
            }
            float bb = bias[col];
            if (y == 3) {
#pragma unroll
                for (int mf = 0; mf < 2; ++mf)
#pragma unroll
                    for (int r = 0; r < 4; ++r) {
                        int row = rbase + mf * 16 + r;
                        if (row < n) oskip[(size_t)row * 128 + col] = acc[mf][r] + bb;
                    }
            } else if (y == 0) {
#pragma unroll
                for (int mf = 0; mf < 2; ++mf)
#pragma unroll
                    for (int r = 0; r < 4; ++r) {
                        int row = rbase + mf * 16 + r;
                        if (row < n)
                            oq16[(size_t)row * 128 + col] = bf16rne(acc[mf][r] + bb);
                    }
            } else {
                const int voff = (y == 2) ? 128 : 0;
#pragma unroll
                for (int mf = 0; mf < 2; ++mf)
#pragma unroll
                    for (int r = 0; r < 4; ++r) {
                        int row = rbase + mf * 16 + r;
                        if (row < n)
                            okv[(size_t)row * 256 + voff + col] = bf16rne(acc[mf][r] + bb);
                    }
            }
        }
    }
}

// ---------------------------------------------------------------------------
// Per-target edge attention, online softmax. Two 32-lane halves per wave, each
// owning one edge (4 feats/lane); states merged via shfl_xor(32). Guarded
// prefetch, 2-chunk pipeline. q read as bf16 (halves q traffic).
// ---------------------------------------------------------------------------
__global__ __launch_bounds__(256) void attn_kernel(
    const unsigned short* __restrict__ q16, const unsigned short* __restrict__ kv,
    const int* __restrict__ rowptr, const int* __restrict__ esrc,
    float* __restrict__ h2, int n) {
    int wid = (blockIdx.x * blockDim.x + threadIdx.x) >> 6;
    int lane = threadIdx.x & 63;
    if (wid >= n) return;
    const int g = lane >> 5;       // half id: edge j+g
    const int f0 = (lane & 31) * 4;
    uint2 qw = *(const uint2*)(q16 + (size_t)wid * 128 + f0);
    float4 qv;
    qv.x = __uint_as_float(qw.x << 16);
    qv.y = __uint_as_float(qw.x & 0xFFFF0000u);
    qv.z = __uint_as_float(qw.y << 16);
    qv.w = __uint_as_float(qw.y & 0xFFFF0000u);
    const float scale = 0.08838834764831845f;  // 1/sqrt(128)
    int beg = rowptr[wid], end = rowptr[wid + 1];
    if (beg == end) return;  // no in-edges: h2 stays = skip term (matches ref)
    float m = -3.402823466e38f, ssum = 0.f;
    float a0 = 0.f, a1 = 0.f, a2 = 0.f, a3 = 0.f;

#define FETCH(J, KU, VU) {                                                   \
        int jj = (J) + g;                                                    \
        if (jj < end) {                                                      \
            int s = esrc[jj];                                                \
            const unsigned short* p = kv + (size_t)s * 256 + f0;             \
            KU = *(const uint2*)p;                                           \
            VU = *(const uint2*)(p + 128);                                   \
        } else { KU.x = 0u; KU.y = 0u; VU.x = 0u; VU.y = 0u; } }

#define PROC(J, KU, VU) {                                                    \
        float kx0 = __uint_as_float(KU.x << 16);                             \
        float kx1 = __uint_as_float(KU.x & 0xFFFF0000u);                     \
        float kx2 = __uint_as_float(KU.y << 16);                             \
        float kx3 = __uint_as_float(KU.y & 0xFFFF0000u);                     \
        float d = qv.x * kx0 + qv.y * kx1 + qv.z * kx2 + qv.w * kx3;         \
        d += __shfl_xor(d, 1);  d += __shfl_xor(d, 2);  d += __shfl_xor(d, 4); \
        d += __shfl_xor(d, 8);  d += __shfl_xor(d, 16);                      \
        d *= scale;                                                          \
        if ((J) + g < end) {                                                 \
            if (d > m) {                                                     \
                float r = __expf(m - d);                                     \
                ssum *= r; a0 *= r; a1 *= r; a2 *= r; a3 *= r; m = d;        \
            }                                                                \
            float w = __expf(d - m);                                         \
            ssum += w;                                                       \
            a0 += w * __uint_as_float(VU.x << 16);                           \
            a1 += w * __uint_as_float(VU.x & 0xFFFF0000u);                   \
            a2 += w * __uint_as_float(VU.y << 16);                           \
            a3 += w * __uint_as_float(VU.y & 0xFFFF0000u);                   \
        } }

    uint2 kA, vA, kB, vB;
    FETCH(beg, kA, vA);
    FETCH(beg + 2, kB, vB);
    int j = beg;
    for (;;) {
        {
            uint2 kN, vN;
            FETCH(j + 4, kN, vN);
            PROC(j, kA, vA);
            kA = kN; vA = vN;
        }
        j += 2; if (j >= end) break;
        {
            uint2 kN, vN;
            FETCH(j + 4, kN, vN);
            PROC(j, kB, vB);
            kB = kN; vB = vN;
        }
        j += 2; if (j >= end) break;
    }
#undef FETCH
#undef PROC

    // merge the two halves' online-softmax states (butterfly, both get result)
    float mo = __shfl_xor(m, 32);
    float m2 = fmaxf(m, mo);
    float fac = __expf(m - m2);      // 0 if this half processed no edges
    ssum *= fac; a0 *= fac; a1 *= fac; a2 *= fac; a3 *= fac;
    ssum += __shfl_xor(ssum, 32);
    a0 += __shfl_xor(a0, 32);
    a1 += __shfl_xor(a1, 32);
    a2 += __shfl_xor(a2, 32);
    a3 += __shfl_xor(a3, 32);
    if (lane < 32) {
        float inv = 1.f / ssum;
        float4* o = (float4*)(h2 + (size_t)wid * 128 + f0);
        float4 cur = *o;
        cur.x += a0 * inv;
        cur.y += a1 * inv;
        cur.z += a2 * inv;
        cur.w += a3 * inv;
        *o = cur;
    }
}

// ---------------------------------------------------------------------------
// BatchNorm stats: vectorized float4 loads, BN_BLOCKS blocks.
// ---------------------------------------------------------------------------
__global__ __launch_bounds__(256) void bn_stats(const float* __restrict__ h2,
                                                float* __restrict__ psum,
                                                float* __restrict__ psq, int n) {
    int q4 = (threadIdx.x & 31) * 4;
    int rp = threadIdx.x >> 5;  // 0..7
    float4 s = make_float4(0.f, 0.f, 0.f, 0.f);
    float4 s2 = make_float4(0.f, 0.f, 0.f, 0.f);
    for (int r = blockIdx.x * 8 + rp; r < n; r += gridDim.x * 8) {
        float4 x = *(const float4*)(h2 + (size_t)r * 128 + q4);
        s.x += x.x; s.y += x.y; s.z += x.z; s.w += x.w;
        s2.x += x.x * x.x; s2.y += x.y * x.y; s2.z += x.z * x.z; s2.w += x.w * x.w;
    }
    __shared__ float4 smS[256], smQ[256];
    smS[threadIdx.x] = s;
    smQ[threadIdx.x] = s2;
    __syncthreads();
    if (rp == 0) {
        int t = threadIdx.x;  // 0..31
#pragma unroll
        for (int i = 1; i < 8; ++i) {
            float4 a = smS[t + 32 * i], b = smQ[t + 32 * i];
            s.x += a.x; s.y += a.y; s.z += a.z; s.w += a.w;
            s2.x += b.x; s2.y += b.y; s2.z += b.z; s2.w += b.w;
        }
        *(float4*)(psum + (size_t)blockIdx.x * 128 + q4) = s;
        *(float4*)(psq + (size_t)blockIdx.x * 128 + q4) = s2;
    }
}

__global__ __launch_bounds__(512) void bn_finalize(const float* __restrict__ psum,
                                                   const float* __restrict__ psq,
                                                   const float* __restrict__ g,
                                                   const float* __restrict__ b,
                                                   float* __restrict__ scale,
                                                   float* __restrict__ shift,
                                                   int n, int nblk) {
    int f = threadIdx.x & 127, part = threadIdx.x >> 7;
    float s = 0.f, s2 = 0.f;
    for (int i = part; i < nblk; i += 4) {
        s += psum[i * 128 + f];
        s2 += psq[i * 128 + f];
    }
    __shared__ float sa[512], sb[512];
    sa[threadIdx.x] = s;
    sb[threadIdx.x] = s2;
    __syncthreads();
    if (part == 0) {
        s = sa[f] + sa[128 + f] + sa[256 + f] + sa[384 + f];
        s2 = sb[f] + sb[128 + f] + sb[256 + f] + sb[384 + f];
        float inv_n = 1.f / (float)n;
        float mu = s * inv_n;
        float var = s2 * inv_n - mu * mu;
        float sc = g[f] * rsqrtf(var + 1e-5f);
        scale[f] = sc;
        shift[f] = b[f] - mu * sc;
    }
}

// ---------------------------------------------------------------------------
// Pool (fused last BN+ReLU) + head
// ---------------------------------------------------------------------------
__global__ __launch_bounds__(256) void pool_kernel(const float* __restrict__ h,
                                                   const float* __restrict__ bnsc,
                                                   const float* __restrict__ bnsh,
                                                   const int* __restrict__ batch,
                                                   float* __restrict__ pooled, int n) {
    int g = blockIdx.x;
    int lo = 0, hi = n;
    while (lo < hi) { int mid = (lo + hi) >> 1; if (batch[mid] < g) lo = mid + 1; else hi = mid; }
    int start = lo;
    lo = start; hi = n;
    while (lo < hi) { int mid = (lo + hi) >> 1; if (batch[mid] < g + 1) lo = mid + 1; else hi = mid; }
    int end = lo;
    int f = threadIdx.x & 127, rp = threadIdx.x >> 7;
    float sc = bnsc[f], sh = bnsh[f];
    float s = 0.f;
    for (int r = start + rp; r < end; r += 2)
        s += fmaxf(0.f, fmaf(h[(size_t)r * 128 + f], sc, sh));
    __shared__ float sm[256];
    sm[threadIdx.x] = s;
    __syncthreads();
    if (rp == 0) {
        float tot = sm[f] + sm[128 + f];
        float cnt = (float)(end - start);
        pooled[g * 128 + f] = tot / fmaxf(cnt, 1.f);
    }
}

__global__ void head_kernel(const float* __restrict__ pooled, const float* __restrict__ W,
                            const float* __restrict__ bias, float* __restrict__ out) {
    int g = blockIdx.x;
    int lane = threadIdx.x;  // 64
    float p0 = pooled[g * 128 + lane];
    float p1 = pooled[g * 128 + 64 + lane];
#pragma unroll
    for (int c = 0; c < C_CLASSES; ++c) {
        float d = p0 * W[lane * C_CLASSES + c] + p1 * W[(64 + lane) * C_CLASSES + c];
#pragma unroll
        for (int off = 32; off; off >>= 1) d += __shfl_xor(d, off);
        if (lane == 0) out[g * C_CLASSES + c] = d + bias[c];
    }
}

// ---------------------------------------------------------------------------
extern "C" void kernel_launch(void* const* d_in, const int* in_sizes, int n_in,
                              void* d_out, int out_size, void* d_ws, size_t ws_size,
                              hipStream_t stream) {
    const int N = in_sizes[0] / IN_DIM;       // 100000
    const int E = in_sizes[1] / 2;            // 600000

    const float* x     = (const float*)d_in[0];
    const int* ei      = (const int*)d_in[1];
    const int* src     = ei;
    const int* dst     = ei + E;
    const int* batch   = (const int*)d_in[2];
    const float* Wq1 = (const float*)d_in[3],  *bq1 = (const float*)d_in[4];
    const float* Wk1 = (const float*)d_in[5],  *bk1 = (const float*)d_in[6];
    const float* Wv1 = (const float*)d_in[7],  *bv1 = (const float*)d_in[8];
    const float* Ws1 = (const float*)d_in[9],  *bs1 = (const float*)d_in[10];
    const float* bn1g = (const float*)d_in[11], *bn1b = (const float*)d_in[12];
    const float* Wq = (const float*)d_in[13], *bq = (const float*)d_in[14];
    const float* Wk = (const float*)d_in[15], *bk = (const float*)d_in[16];
    const float* Wv = (const float*)d_in[17], *bv = (const float*)d_in[18];
    const float* Ws = (const float*)d_in[19], *bs = (const float*)d_in[20];
    const float* bng = (const float*)d_in[21], *bnb = (const float*)d_in[22];
    const float* linW = (const float*)d_in[23], *linb = (const float*)d_in[24];
    float* out = (float*)d_out;

    const int strips = (N + 31) / 32;         // 3125 (N % 32 == 0)

    // workspace layout
    char* w = (char*)d_ws;
    auto alloc = [&](size_t bytes) -> char* {
        char* p = w;
        w += (bytes + 255) & ~(size_t)255;
        return p;
    };
    const size_t NH = (size_t)N * H_DIM;
    unsigned short* q16 = (unsigned short*)alloc(NH * 2);
    float* convA = (float*)alloc(NH * 4);
    float* convB = (float*)alloc(NH * 4);
    unsigned short* kv16 = (unsigned short*)alloc((size_t)N * 256 * 2);
    unsigned short* WF   = (unsigned short*)alloc((size_t)(65536 + 12 * 32768) * 2);
    float* psum = (float*)alloc((size_t)BN_BLOCKS * 128 * 4);
    float* psq  = (float*)alloc((size_t)BN_BLOCKS * 128 * 4);
    float* bnsc = (float*)alloc(128 * 4);
    float* bnsh = (float*)alloc(128 * 4);
    float* pooled = (float*)alloc(G_GRAPHS * H_DIM * 4);
    int* deg    = (int*)alloc((size_t)N * 4);
    int* rowptr = (int*)alloc((size_t)(N + 1) * 4);
    int* erank  = (int*)alloc((size_t)E * 4);
    int* esrc   = (int*)alloc((size_t)E * 4);
    int* bsum   = (int*)alloc(((size_t)(N + 255) / 256) * 4);

    const int nblk = (N + 255) / 256;
    const int egrid = (E + 255) / 256;

    // ---- CSR build + all weight prep (independent, up-front)
    hipMemsetAsync(deg, 0, (size_t)N * 4, stream);
    count_deg<<<egrid, 256, 0, stream>>>(dst, deg, erank, E);
    prep_w64<<<dim3(4, 4), 256, 0, stream>>>(Wq1, Wk1, Wv1, Ws1, WF);
    prep_w128<<<dim3(8, 12), 256, 0, stream>>>(Wq, Wk, Wv, Ws, WF);
    scan1<<<nblk, 256, 0, stream>>>(deg, rowptr, bsum, N);
    scan2<<<1, 512, 0, stream>>>(bsum, nblk);
    scan3<<<nblk, 256, 0, stream>>>(rowptr, bsum, N);
    scatter_edges<<<egrid, 256, 0, stream>>>(src, dst, rowptr, erank, esrc, E);

    const int attn_blocks = (N + 3) / 4;
    const int gemm_blocks = (strips + 3) / 4;

    // ---- layer 1 (K=64, raw input, no BN)
    gemm_fused<IN_DIM, false><<<gemm_blocks, 256, 0, stream>>>(
        x, WF, N, strips, nullptr, nullptr, bq1, bk1, bv1, bs1, q16, kv16, convA);
    attn_kernel<<<attn_blocks, 256, 0, stream>>>(q16, kv16, rowptr, esrc, convA, N);
    bn_stats<<<BN_BLOCKS, 256, 0, stream>>>(convA, psum, psq, N);
    bn_finalize<<<1, 512, 0, stream>>>(psum, psq, bn1g, bn1b, bnsc, bnsh, N, BN_BLOCKS);

    // ---- layers 2..4 (K=128, prev BN+ReLU fused into gemm A-load)
    float* cur = convA;
    float* nxt = convB;
    for (int i = 0; i < L_LAYERS; ++i) {
        const size_t bo = (size_t)i * H_DIM;
        const unsigned short* WFl = WF + 65536 + (size_t)i * 4 * 32768;
        gemm_fused<H_DIM, true><<<gemm_blocks, 256, 0, stream>>>(
            cur, WFl, N, strips, bnsc, bnsh, bq + bo, bk + bo, bv + bo, bs + bo,
            q16, kv16, nxt);
        attn_kernel<<<attn_blocks, 256, 0, stream>>>(q16, kv16, rowptr, esrc, nxt, N);
        bn_stats<<<BN_BLOCKS, 256, 0, stream>>>(nxt, psum, psq, N);
        bn_finalize<<<1, 512, 0, stream>>>(psum, psq, bng + bo, bnb + bo, bnsc, bnsh, N, BN_BLOCKS);
        float* t = cur; cur = nxt; nxt = t;
    }

    // ---- pool (fused last BN+ReLU) + head
    pool_kernel<<<G_GRAPHS, 256, 0, stream>>>(cur, bnsc, bnsh, batch, pooled, N);
    head_kernel<<<G_GRAPHS, 64, 0, stream>>>(pooled, linW, linb, out);
}